// Round 4
// baseline (228.570 us; speedup 1.0000x reference)
//
#include <hip/hip_runtime.h>
#include <hip/hip_bf16.h>
#include <stdint.h>

// Problem constants: B=4, N=M=2048, C=512, H=4, D_QK=256, D_V=128
#define SCALE_F 0.08838834764831845f  // 1/sqrt(128)

typedef __attribute__((ext_vector_type(8))) short short8;
typedef __attribute__((ext_vector_type(4))) float f32x4;
typedef __attribute__((ext_vector_type(16))) float f32x16;

__device__ __forceinline__ void g2l16(const void* g, void* l) {
  __builtin_amdgcn_global_load_lds(
      (const __attribute__((address_space(1))) void*)g,
      (__attribute__((address_space(3))) void*)l, 16, 0, 0);
}

__device__ __forceinline__ float bf2f(unsigned short s) {
  union { unsigned int i; float f; } c; c.i = ((unsigned int)s) << 16; return c.f;
}

// ---------------- fp32 -> bf16 conversion (x, context, W_qkv, W_proj) --------
__global__ __launch_bounds__(256) void convert_all(
    const float* __restrict__ x, const float* __restrict__ ctx,
    const float* __restrict__ wqkv, const float* __restrict__ wproj,
    __hip_bfloat16* __restrict__ ab, __hip_bfloat16* __restrict__ wb,
    __hip_bfloat16* __restrict__ wpb)
{
  size_t qi = (size_t)blockIdx.x * 256 + threadIdx.x;  // quad index
  const float* src; __hip_bfloat16* dst; size_t off;
  if (qi < 1048576)      { src = x;     dst = ab;           off = qi; }
  else if (qi < 2097152) { src = ctx;   dst = ab + 4194304; off = qi - 1048576; }
  else if (qi < 2228224) { src = wqkv;  dst = wb;           off = qi - 2097152; }
  else                   { src = wproj; dst = wpb;          off = qi - 2228224; }
  float4 v = ((const float4*)src)[off];
  union { __hip_bfloat16 h4[4]; uint2 u; } o;
  o.h4[0] = __float2bfloat16(v.x); o.h4[1] = __float2bfloat16(v.y);
  o.h4[2] = __float2bfloat16(v.z); o.h4[3] = __float2bfloat16(v.w);
  ((uint2*)dst)[off] = o.u;
}

// ---------------- V transpose: context (b,m,h*128+d) -> vt (bh, d, m) --------
__global__ __launch_bounds__(256) void transpose_v(
    const float* __restrict__ ctx, __hip_bfloat16* __restrict__ vt)
{
  __shared__ float tile[128][33];
  const int bid = blockIdx.x;          // B*H*64 = 1024
  const int mt = bid & 63;
  const int bh = bid >> 6;
  const int h = bh & 3, b = bh >> 2;
  const int tid = threadIdx.x;
  for (int i = 0; i < 16; ++i) {
    int idx = i * 256 + tid;
    int mm = idx >> 7, d = idx & 127;
    tile[d][mm] = ctx[((size_t)b * 2048 + mt * 32 + mm) * 512 + h * 128 + d];
  }
  __syncthreads();
  for (int i = 0; i < 16; ++i) {
    int idx = i * 256 + tid;
    int d = idx >> 5, mm = idx & 31;
    vt[((size_t)bh * 128 + d) * 2048 + mt * 32 + mm] = __float2bfloat16(tile[d][mm]);
  }
}

// ---------------- NT GEMM: C[r,o] = sum_k A[r,k]*B[o,k], templated output ----
template <typename OUT>
__global__ __launch_bounds__(256) void gemm_nt(
    const __hip_bfloat16* __restrict__ A, const __hip_bfloat16* __restrict__ B,
    OUT* __restrict__ C, int O, int K, int tiles_o)
{
  __shared__ __hip_bfloat16 sA[128 * 32];
  __shared__ __hip_bfloat16 sB[128 * 32];
  const int tid = threadIdx.x;
  const int wave = tid >> 6, lane = tid & 63;
  const int ln = lane & 15, q = lane >> 4;
  const int br = (blockIdx.x / tiles_o) * 128;
  const int bo = (blockIdx.x % tiles_o) * 128;
  const int wr = (wave >> 1) * 64, wc = (wave & 1) * 64;
  const __hip_bfloat16* Ab = A + (size_t)br * K;
  const __hip_bfloat16* Bb = B + (size_t)bo * K;
  const int row0 = tid >> 2, p0 = tid & 3;
  f32x4 acc[4][4] = {};
  for (int k0 = 0; k0 < K; k0 += 32) {
    for (int i = 0; i < 2; ++i) {
      int row = i * 64 + row0;
      g2l16(Ab + (size_t)row * K + k0 + p0 * 8, (char*)sA + (i * 256 + tid) * 16);
      g2l16(Bb + (size_t)row * K + k0 + p0 * 8, (char*)sB + (i * 256 + tid) * 16);
    }
    __syncthreads();
    short8 af[4], bfr[4];
    for (int mi = 0; mi < 4; ++mi)
      af[mi] = *(const short8*)(sA + (wr + mi * 16 + ln) * 32 + q * 8);
    for (int ni = 0; ni < 4; ++ni)
      bfr[ni] = *(const short8*)(sB + (wc + ni * 16 + ln) * 32 + q * 8);
    for (int mi = 0; mi < 4; ++mi)
      for (int ni = 0; ni < 4; ++ni)
        acc[mi][ni] = __builtin_amdgcn_mfma_f32_16x16x32_bf16(af[mi], bfr[ni], acc[mi][ni], 0, 0, 0);
    __syncthreads();
  }
  for (int mi = 0; mi < 4; ++mi)
    for (int ni = 0; ni < 4; ++ni) {
      int rg = br + wr + mi * 16 + q * 4;
      int cg = bo + wc + ni * 16 + ln;
      for (int r = 0; r < 4; ++r) {
        float v = acc[mi][ni][r];
        if constexpr (sizeof(OUT) == 2)
          C[(size_t)(rg + r) * O + cg] = __float2bfloat16(v);
        else
          C[(size_t)(rg + r) * O + cg] = v;
      }
    }
}

// ---------------- l2norm + radius/scale fold, bf16 -> bf16 -------------------
__global__ __launch_bounds__(256) void normalize_qk(
    const __hip_bfloat16* __restrict__ proj, const float* __restrict__ radius,
    __hip_bfloat16* __restrict__ qn, __hip_bfloat16* __restrict__ kn)
{
  const int r = blockIdx.x;
  const int h = threadIdx.x >> 6, lane = threadIdx.x & 63;
  union { uint2 u; unsigned short s[4]; } pu;
  pu.u = *(const uint2*)(proj + (size_t)r * 1024 + h * 256 + lane * 4);
  float v0 = bf2f(pu.s[0]), v1 = bf2f(pu.s[1]), v2 = bf2f(pu.s[2]), v3 = bf2f(pu.s[3]);
  float ss = v0 * v0 + v1 * v1 + v2 * v2 + v3 * v3;
  for (int off = 1; off < 64; off <<= 1) ss += __shfl_xor(ss, off);
  float nrm = fmaxf(sqrtf(ss), 1e-12f);
  const bool isq = r < 8192;
  const int rr = isq ? r : r - 8192;
  const float rad = radius[h];
  const float sc = (isq ? rad * rad * SCALE_F : 1.0f) / nrm;
  __hip_bfloat16* dst = (isq ? qn : kn) +
      ((size_t)((rr >> 11) * 4 + h) * 2048 + (rr & 2047)) * 256 + lane * 4;
  union { __hip_bfloat16 h4[4]; uint2 u; } o;
  o.h4[0] = __float2bfloat16(v0 * sc);
  o.h4[1] = __float2bfloat16(v1 * sc);
  o.h4[2] = __float2bfloat16(v2 * sc);
  o.h4[3] = __float2bfloat16(v3 * sc);
  *(uint2*)dst = o.u;
}

// ---------------- flash attention v4: producer/consumer waves ----------------
// 2 QK waves (64 q-rows each, qf resident) produce P; 2 PV waves (64 d-cols
// each) consume P and accumulate O. P single-buffered, 2 barriers/iter.
// K-tile LDS redundancy 4->2, V 4->1. Roles flipped by blockIdx>>8 so the two
// co-resident blocks/CU put QK and PV on complementary SIMDs.
// grid = 512: bh(16) x nt(16) x half(2), XCD-swizzled.
__global__ __launch_bounds__(256, 2) void attn(
    const __hip_bfloat16* __restrict__ qn,  // (bh, 2048, 256)
    const __hip_bfloat16* __restrict__ kn,  // (bh, 2048, 256)
    const __hip_bfloat16* __restrict__ vt,  // (bh, 128, 2048)
    float* __restrict__ Op,                 // (half, bh, 2048, 128) fp32
    float* __restrict__ den)                // (half, bh, 2048) fp32
{
  __shared__ __hip_bfloat16 sK[2][32 * 256];  // 32KB; row=512B, swz c^=(row&7)
  __shared__ __hip_bfloat16 sV[2][128 * 32];  // 16KB; row=64B, swz c^=((row>>1)&3)
  __shared__ __hip_bfloat16 sP[128 * 40];     // 10KB; rows padded to 40 elems
  const int tid = threadIdx.x, wave = tid >> 6, lane = tid & 63;
  const int m32 = lane & 31, hi = lane >> 5;
  const int i = blockIdx.x;
  const int bh = (i & 7) + 8 * ((i >> 3) & 1);
  const int half = (i >> 4) & 1;
  const int nt = i >> 5;
  const int mbase = half * 1024;
  const int flip = (i >> 8) & 1;
  const bool isQK = ((wave >> 1) ^ flip) == 0;
  const int wsub = wave & 1;
  const __hip_bfloat16* Kp = kn + (size_t)bh * 2048 * 256;
  const __hip_bfloat16* Vp = vt + (size_t)bh * 128 * 2048;

  if (isQK) {
    // ---------------- producer: S = Q K^T, exp, P + denom -------------------
    short8 qf[2][16];   // rows wsub*64 + sub*32 + [0,32)
    const __hip_bfloat16* Q = qn + ((size_t)bh * 2048 + nt * 128 + wsub * 64) * 256;
    for (int sub = 0; sub < 2; ++sub)
      for (int kk = 0; kk < 16; ++kk)
        qf[sub][kk] = *(const short8*)(Q + (sub * 32 + m32) * 256 + kk * 16 + hi * 8);
    float dn0[16], dn1[16];
    for (int j = 0; j < 16; ++j) { dn0[j] = 0.f; dn1[j] = 0.f; }
    __syncthreads();                       // matches PV prologue barrier
    for (int it = 0; it < 32; ++it) {
      const __hip_bfloat16* sKc = sK[it & 1];
      f32x16 s0, s1;
      for (int j = 0; j < 16; ++j) { s0[j] = 0.f; s1[j] = 0.f; }
      for (int kk = 0; kk < 16; ++kk) {
        int c = kk * 2 + hi;
        short8 kf = *(const short8*)(sKc + m32 * 256 + ((c ^ (m32 & 7)) << 3));
        s0 = __builtin_amdgcn_mfma_f32_32x32x16_bf16(qf[0][kk], kf, s0, 0, 0, 0);
        s1 = __builtin_amdgcn_mfma_f32_32x32x16_bf16(qf[1][kk], kf, s1, 0, 0, 0);
      }
      for (int reg = 0; reg < 16; ++reg) {
        int r0 = wsub * 64 + (reg & 3) + 8 * (reg >> 2) + 4 * hi;
        float e0 = __expf(s0[reg]), e1 = __expf(s1[reg]);
        dn0[reg] += e0; dn1[reg] += e1;
        sP[r0 * 40 + m32] = __float2bfloat16(e0);
        sP[(r0 + 32) * 40 + m32] = __float2bfloat16(e1);
      }
      __syncthreads();   // barrier1: P visible to PV waves
      __syncthreads();   // barrier2: PV finished reading P
    }
    // denom: reduce across the 32 ctx-col lanes, write
    for (int reg = 0; reg < 16; ++reg)
      for (int off = 1; off < 32; off <<= 1) {
        dn0[reg] += __shfl_xor(dn0[reg], off);
        dn1[reg] += __shfl_xor(dn1[reg], off);
      }
    if (m32 == 0) {
      float* denb = den + (size_t)(half * 16 + bh) * 2048 + nt * 128;
      for (int reg = 0; reg < 16; ++reg) {
        int r0 = wsub * 64 + (reg & 3) + 8 * (reg >> 2) + 4 * hi;
        denb[r0] = dn0[reg];
        denb[r0 + 32] = dn1[reg];
      }
    }
  } else {
    // ---------------- consumer: O += P V (d-cols wsub*64..+63) --------------
    f32x16 oacc[4][2];
    for (int a = 0; a < 4; ++a)
      for (int b2 = 0; b2 < 2; ++b2)
        for (int j = 0; j < 16; ++j) oacc[a][b2][j] = 0.f;
    // prologue: stage K[0], V[0] -> buf0 (PV waves only; 12 g2l per thread)
    for (int j = 0; j < 8; ++j) {
      int D = j * 128 + wsub * 64 + lane;
      int row = D >> 5, cc = D & 31;
      g2l16(Kp + (size_t)(mbase + row) * 256 + ((cc ^ (row & 7)) << 3),
            (char*)sK[0] + D * 16);
    }
    for (int j = 0; j < 4; ++j) {
      int D = j * 128 + wsub * 64 + lane;
      int rd = D >> 2, cc = D & 3;
      g2l16(Vp + (size_t)rd * 2048 + mbase + ((cc ^ ((rd >> 1) & 3)) << 3),
            (char*)sV[0] + D * 16);
    }
    __syncthreads();                       // prologue barrier
    for (int it = 0; it < 32; ++it) {
      const int cur = it & 1, nxt = cur ^ 1;
      if (it + 1 < 32) {                   // prefetch next K/V tiles
        const int m1 = mbase + (it + 1) * 32;
        for (int j = 0; j < 8; ++j) {
          int D = j * 128 + wsub * 64 + lane;
          int row = D >> 5, cc = D & 31;
          g2l16(Kp + (size_t)(m1 + row) * 256 + ((cc ^ (row & 7)) << 3),
                (char*)sK[nxt] + D * 16);
        }
        for (int j = 0; j < 4; ++j) {
          int D = j * 128 + wsub * 64 + lane;
          int rd = D >> 2, cc = D & 3;
          g2l16(Vp + (size_t)rd * 2048 + m1 + ((cc ^ ((rd >> 1) & 3)) << 3),
                (char*)sV[nxt] + D * 16);
        }
      }
      __syncthreads();   // barrier1: P[it] ready, prefetch drained
      const __hip_bfloat16* sVc = sV[cur];
      for (int kc = 0; kc < 2; ++kc) {
        short8 vf0, vf1;
        {
          int rd0 = wsub * 64 + m32, rd1 = wsub * 64 + 32 + m32;
          int c = kc * 2 + hi;
          vf0 = *(const short8*)(sVc + rd0 * 32 + ((c ^ ((rd0 >> 1) & 3)) << 3));
          vf1 = *(const short8*)(sVc + rd1 * 32 + ((c ^ ((rd1 >> 1) & 3)) << 3));
        }
        for (int ms = 0; ms < 4; ++ms) {
          short8 pf = *(const short8*)(sP + (ms * 32 + m32) * 40 + kc * 16 + hi * 8);
          oacc[ms][0] = __builtin_amdgcn_mfma_f32_32x32x16_bf16(pf, vf0, oacc[ms][0], 0, 0, 0);
          oacc[ms][1] = __builtin_amdgcn_mfma_f32_32x32x16_bf16(pf, vf1, oacc[ms][1], 0, 0, 0);
        }
      }
      __syncthreads();   // barrier2: P consumed, buffers swappable
    }
    // epilogue: write unnormalized partial O
    float* Opb = Op + ((size_t)(half * 16 + bh) * 2048 + nt * 128) * 128;
    for (int ms = 0; ms < 4; ++ms)
      for (int ns = 0; ns < 2; ++ns)
        for (int reg = 0; reg < 16; ++reg) {
          int row = ms * 32 + (reg & 3) + 8 * (reg >> 2) + 4 * hi;
          int col = wsub * 64 + ns * 32 + m32;
          Opb[(size_t)row * 128 + col] = oacc[ms][ns][reg];
        }
  }
}

// ---------------- combine ctx halves -> bf16 ob ------------------------------
__global__ __launch_bounds__(256) void combine(
    const float* __restrict__ Op, const float* __restrict__ den,
    __hip_bfloat16* __restrict__ ob)
{
  int qi = blockIdx.x * 256 + threadIdx.x;   // 1,048,576 float4-quads
  int r = qi >> 5, dq = qi & 31;
  int bh = r >> 11, n = r & 2047, b = bh >> 2, h = bh & 3;
  float4 o0 = ((const float4*)Op)[qi];
  float4 o1 = ((const float4*)(Op + 4194304))[qi];
  float inv = 1.0f / (den[r] + den[32768 + r]);
  union { __hip_bfloat16 h4[4]; uint2 u; } o;
  o.h4[0] = __float2bfloat16((o0.x + o1.x) * inv);
  o.h4[1] = __float2bfloat16((o0.y + o1.y) * inv);
  o.h4[2] = __float2bfloat16((o0.z + o1.z) * inv);
  o.h4[3] = __float2bfloat16((o0.w + o1.w) * inv);
  *(uint2*)&ob[((size_t)b * 2048 + n) * 512 + h * 128 + dq * 4] = o.u;
}

// ---------------- launch ------------------------------------------------------
extern "C" void kernel_launch(void* const* d_in, const int* in_sizes, int n_in,
                              void* d_out, int out_size, void* d_ws, size_t ws_size,
                              hipStream_t stream) {
  const float* x      = (const float*)d_in[0];
  const float* ctx    = (const float*)d_in[1];
  const float* wqkv   = (const float*)d_in[2];
  const float* wproj  = (const float*)d_in[3];
  const float* radius = (const float*)d_in[4];
  char* ws = (char*)d_ws;
  __hip_bfloat16* ab  = (__hip_bfloat16*)(ws);              // 16 MB (x+ctx bf16)
  __hip_bfloat16* wb  = (__hip_bfloat16*)(ws + 16777216);   // 1 MB
  __hip_bfloat16* wpb = (__hip_bfloat16*)(ws + 17825792);   // 0.5 MB
  __hip_bfloat16* proj= (__hip_bfloat16*)(ws + 18350080);   // 32 MB bf16 (region 64MB)
  float*          Op  = (float*)(ws + 18350080);            // 33.5 MB partial O (reuse, dead proj)
  float*          den = (float*)(ws + 18350080 + 33554432); // 256 KB partial denom
  __hip_bfloat16* qn  = (__hip_bfloat16*)(ws + 85458944);   // 16 MB
  __hip_bfloat16* kn  = (__hip_bfloat16*)(ws + 102236160);  // 16 MB
  __hip_bfloat16* vt  = (__hip_bfloat16*)(ws + 119013376);  // 8 MB
  __hip_bfloat16* ob  = (__hip_bfloat16*)(ws + 127401984);  // 8 MB
  float* out = (float*)d_out;

  convert_all<<<8960, 256, 0, stream>>>(x, ctx, wqkv, wproj, ab, wb, wpb);
  transpose_v<<<1024, 256, 0, stream>>>(ctx, vt);
  gemm_nt<__hip_bfloat16><<<1024, 256, 0, stream>>>(ab, wb, proj, 1024, 512, 8);
  normalize_qk<<<16384, 256, 0, stream>>>(proj, radius, qn, kn);
  attn<<<512, 256, 0, stream>>>(qn, kn, vt, Op, den);
  combine<<<4096, 256, 0, stream>>>(Op, den, ob);
  gemm_nt<float><<<256, 256, 0, stream>>>(ob, wpb, out, 512, 512, 4);
}

// Round 7
// 227.522 us; speedup vs baseline: 1.0046x; 1.0046x over previous
//
#include <hip/hip_runtime.h>
#include <hip/hip_bf16.h>
#include <stdint.h>

// Problem constants: B=4, N=M=2048, C=512, H=4, D_QK=256, D_V=128
#define SCALE_F 0.08838834764831845f  // 1/sqrt(128)

typedef __attribute__((ext_vector_type(8))) short short8;
typedef __attribute__((ext_vector_type(4))) float f32x4;
typedef __attribute__((ext_vector_type(16))) float f32x16;

__device__ __forceinline__ void g2l16(const void* g, void* l) {
  __builtin_amdgcn_global_load_lds(
      (const __attribute__((address_space(1))) void*)g,
      (__attribute__((address_space(3))) void*)l, 16, 0, 0);
}

__device__ __forceinline__ float bf2f(unsigned short s) {
  union { unsigned int i; float f; } c; c.i = ((unsigned int)s) << 16; return c.f;
}

// ---------------- fp32 -> bf16: x, W_qkv, W_proj (ctx handled by ctx_pack) ---
__global__ __launch_bounds__(256) void convert_xw(
    const float* __restrict__ x, const float* __restrict__ wqkv,
    const float* __restrict__ wproj, __hip_bfloat16* __restrict__ ab,
    __hip_bfloat16* __restrict__ wb, __hip_bfloat16* __restrict__ wpb)
{
  size_t qi = (size_t)blockIdx.x * 256 + threadIdx.x;  // quad index, 1245184 total
  const float* src; __hip_bfloat16* dst; size_t off;
  if (qi < 1048576)      { src = x;     dst = ab;  off = qi; }
  else if (qi < 1179648) { src = wqkv;  dst = wb;  off = qi - 1048576; }
  else                   { src = wproj; dst = wpb; off = qi - 1179648; }
  float4 v = ((const float4*)src)[off];
  union { __hip_bfloat16 h4[4]; uint2 u; } o;
  o.h4[0] = __float2bfloat16(v.x); o.h4[1] = __float2bfloat16(v.y);
  o.h4[2] = __float2bfloat16(v.z); o.h4[3] = __float2bfloat16(v.w);
  ((uint2*)dst)[off] = o.u;
}

// ---- ctx: one fp32 read -> vt (bh,d,m) bf16 + ab ctx-half bf16 (fused) ------
__global__ __launch_bounds__(256) void ctx_pack(
    const float* __restrict__ ctx, __hip_bfloat16* __restrict__ vt,
    __hip_bfloat16* __restrict__ ab)
{
  __shared__ float tile[128][33];
  const int bid = blockIdx.x;          // B*H*64 = 1024
  const int mt = bid & 63;
  const int bh = bid >> 6;
  const int h = bh & 3, b = bh >> 2;
  const int tid = threadIdx.x;
  for (int i = 0; i < 16; ++i) {
    int idx = i * 256 + tid;
    int mm = idx >> 7, d = idx & 127;
    size_t gidx = ((size_t)b * 2048 + mt * 32 + mm) * 512 + h * 128 + d;
    float v = ctx[gidx];
    tile[d][mm] = v;
    ab[4194304 + gidx] = __float2bfloat16(v);  // ctx rows start at ab row 8192
  }
  __syncthreads();
  for (int i = 0; i < 16; ++i) {
    int idx = i * 256 + tid;
    int d = idx >> 5, mm = idx & 31;
    vt[((size_t)bh * 128 + d) * 2048 + mt * 32 + mm] = __float2bfloat16(tile[d][mm]);
  }
}

// ---------------- NT GEMM: C[r,o] = sum_k A[r,k]*B[o,k], templated output ----
template <typename OUT>
__global__ __launch_bounds__(256) void gemm_nt(
    const __hip_bfloat16* __restrict__ A, const __hip_bfloat16* __restrict__ B,
    OUT* __restrict__ C, int O, int K, int tiles_o)
{
  __shared__ __hip_bfloat16 sA[128 * 32];
  __shared__ __hip_bfloat16 sB[128 * 32];
  const int tid = threadIdx.x;
  const int wave = tid >> 6, lane = tid & 63;
  const int ln = lane & 15, q = lane >> 4;
  const int br = (blockIdx.x / tiles_o) * 128;
  const int bo = (blockIdx.x % tiles_o) * 128;
  const int wr = (wave >> 1) * 64, wc = (wave & 1) * 64;
  const __hip_bfloat16* Ab = A + (size_t)br * K;
  const __hip_bfloat16* Bb = B + (size_t)bo * K;
  const int row0 = tid >> 2, p0 = tid & 3;
  f32x4 acc[4][4] = {};
  for (int k0 = 0; k0 < K; k0 += 32) {
    for (int i = 0; i < 2; ++i) {
      int row = i * 64 + row0;
      g2l16(Ab + (size_t)row * K + k0 + p0 * 8, (char*)sA + (i * 256 + tid) * 16);
      g2l16(Bb + (size_t)row * K + k0 + p0 * 8, (char*)sB + (i * 256 + tid) * 16);
    }
    __syncthreads();
    short8 af[4], bfr[4];
    for (int mi = 0; mi < 4; ++mi)
      af[mi] = *(const short8*)(sA + (wr + mi * 16 + ln) * 32 + q * 8);
    for (int ni = 0; ni < 4; ++ni)
      bfr[ni] = *(const short8*)(sB + (wc + ni * 16 + ln) * 32 + q * 8);
    for (int mi = 0; mi < 4; ++mi)
      for (int ni = 0; ni < 4; ++ni)
        acc[mi][ni] = __builtin_amdgcn_mfma_f32_16x16x32_bf16(af[mi], bfr[ni], acc[mi][ni], 0, 0, 0);
    __syncthreads();
  }
  for (int mi = 0; mi < 4; ++mi)
    for (int ni = 0; ni < 4; ++ni) {
      int rg = br + wr + mi * 16 + q * 4;
      int cg = bo + wc + ni * 16 + ln;
      for (int r = 0; r < 4; ++r) {
        float v = acc[mi][ni][r];
        if constexpr (sizeof(OUT) == 2)
          C[(size_t)(rg + r) * O + cg] = __float2bfloat16(v);
        else
          C[(size_t)(rg + r) * O + cg] = v;
      }
    }
}

// ---------------- l2norm + radius/scale fold, bf16 -> bf16 -------------------
__global__ __launch_bounds__(256) void normalize_qk(
    const __hip_bfloat16* __restrict__ proj, const float* __restrict__ radius,
    __hip_bfloat16* __restrict__ qn, __hip_bfloat16* __restrict__ kn)
{
  const int r = blockIdx.x;
  const int h = threadIdx.x >> 6, lane = threadIdx.x & 63;
  union { uint2 u; unsigned short s[4]; } pu;
  pu.u = *(const uint2*)(proj + (size_t)r * 1024 + h * 256 + lane * 4);
  float v0 = bf2f(pu.s[0]), v1 = bf2f(pu.s[1]), v2 = bf2f(pu.s[2]), v3 = bf2f(pu.s[3]);
  float ss = v0 * v0 + v1 * v1 + v2 * v2 + v3 * v3;
  for (int off = 1; off < 64; off <<= 1) ss += __shfl_xor(ss, off);
  float nrm = fmaxf(sqrtf(ss), 1e-12f);
  const bool isq = r < 8192;
  const int rr = isq ? r : r - 8192;
  const float rad = radius[h];
  const float sc = (isq ? rad * rad * SCALE_F : 1.0f) / nrm;
  __hip_bfloat16* dst = (isq ? qn : kn) +
      ((size_t)((rr >> 11) * 4 + h) * 2048 + (rr & 2047)) * 256 + lane * 4;
  union { __hip_bfloat16 h4[4]; uint2 u; } o;
  o.h4[0] = __float2bfloat16(v0 * sc);
  o.h4[1] = __float2bfloat16(v1 * sc);
  o.h4[2] = __float2bfloat16(v2 * sc);
  o.h4[3] = __float2bfloat16(v3 * sc);
  *(uint2*)dst = o.u;
}

// ---------------- flash attention v7: per-wave software pipeline -------------
// bf16 32x32x16 MFMA, 32 q-rows/wave. KEY CHANGE vs R3: S(t+1)'s QK chain is
// issued interleaved with exp(t)+PV(t) (independent streams in one basic
// block), so MFMA/VALU/LDS pipes overlap instead of phase-locking. Requires
// K staged 2 ahead -> triple-buffered sK. 74KB LDS, 2 blocks/CU.
// grid = 512: bh(16) x nt(16) x half(2), XCD-swizzled. Partial O + denom out.
__global__ __launch_bounds__(256, 2) void attn(
    const __hip_bfloat16* __restrict__ qn,  // (bh, 2048, 256)
    const __hip_bfloat16* __restrict__ kn,  // (bh, 2048, 256)
    const __hip_bfloat16* __restrict__ vt,  // (bh, 128, 2048)
    float* __restrict__ Op,                 // (half, bh, 2048, 128) fp32
    float* __restrict__ den)                // (half, bh, 2048) fp32
{
  __shared__ __hip_bfloat16 sK[3][32 * 256];  // 3x16KB; row=512B, swz c^=(row&7)
  __shared__ __hip_bfloat16 sV[2][128 * 32];  // 2x8KB; row=64B, swz c^=((row>>1)&3)
  __shared__ __hip_bfloat16 sP[4][32 * 40];   // per-wave P, rows padded to 40
  const int tid = threadIdx.x, wave = tid >> 6, lane = tid & 63;
  const int m32 = lane & 31, hi = lane >> 5;
  const int i = blockIdx.x;
  const int bh = (i & 7) + 8 * ((i >> 3) & 1);
  const int half = (i >> 4) & 1;
  const int nt = i >> 5;
  const int mbase = half * 1024;
  const __hip_bfloat16* Kp = kn + (size_t)bh * 2048 * 256;
  const __hip_bfloat16* Vp = vt + (size_t)bh * 128 * 2048;

  // Q A-frags in registers: A[m=lane&31][k=(lane>>5)*8+j], 16 k-chunks of 16
  short8 qf[16];
  {
    const __hip_bfloat16* Q = qn + ((size_t)bh * 2048 + nt * 128 + wave * 32) * 256;
    for (int kk = 0; kk < 16; ++kk)
      qf[kk] = *(const short8*)(Q + m32 * 256 + kk * 16 + hi * 8);
  }

  f32x16 oacc[4];
  float denom[16];
  for (int v = 0; v < 4; ++v)
    for (int j = 0; j < 16; ++j) oacc[v][j] = 0.f;
  for (int j = 0; j < 16; ++j) denom[j] = 0.f;
  __hip_bfloat16* sPw = sP[wave];

#define STAGE_K(tile, buf)                                                   \
  for (int t = 0; t < 4; ++t) {                                              \
    int D = t * 256 + tid, row = D >> 5, cc = D & 31;                        \
    g2l16(Kp + (size_t)(mbase + (tile) * 32 + row) * 256 + ((cc ^ (row & 7)) << 3), \
          (char*)sK[buf] + D * 16);                                          \
  }
#define STAGE_V(tile, buf)                                                   \
  for (int t = 0; t < 2; ++t) {                                              \
    int D = t * 256 + tid, rd = D >> 2, cc = D & 3;                          \
    g2l16(Vp + (size_t)rd * 2048 + mbase + (tile) * 32 + ((cc ^ ((rd >> 1) & 3)) << 3), \
          (char*)sV[buf] + D * 16);                                          \
  }

  // prologue: tile0 -> (K0,V0), drain; issue K1; QK(0); drain K1
  STAGE_K(0, 0);
  STAGE_V(0, 0);
  __syncthreads();
  STAGE_K(1, 1);
  f32x16 S_cur;
  for (int j = 0; j < 16; ++j) S_cur[j] = 0.f;
  {
    const __hip_bfloat16* sKc = sK[0];
    for (int kk = 0; kk < 16; ++kk) {
      int c = kk * 2 + hi;
      short8 kf = *(const short8*)(sKc + m32 * 256 + ((c ^ (m32 & 7)) << 3));
      S_cur = __builtin_amdgcn_mfma_f32_32x32x16_bf16(qf[kk], kf, S_cur, 0, 0, 0);
    }
  }
  __syncthreads();

  for (int it = 0; it < 32; ++it) {
    // stage K[it+2] / V[it+1] (drained by this iter's end barrier)
    if (it + 2 < 32) { STAGE_K(it + 2, (it + 2) % 3); }
    if (it + 1 < 32) { STAGE_V(it + 1, (it + 1) & 1); }
    // QK(it+1): independent MFMA+LDS stream, interleaves with exp/PV below
    f32x16 S_next;
    for (int j = 0; j < 16; ++j) S_next[j] = 0.f;
    if (it + 1 < 32) {
      const __hip_bfloat16* sKc = sK[(it + 1) % 3];
      for (int kk = 0; kk < 16; ++kk) {
        int c = kk * 2 + hi;
        short8 kf = *(const short8*)(sKc + m32 * 256 + ((c ^ (m32 & 7)) << 3));
        S_next = __builtin_amdgcn_mfma_f32_32x32x16_bf16(qf[kk], kf, S_next, 0, 0, 0);
      }
    }
    // exp(S_cur) -> P + denom
    for (int reg = 0; reg < 16; ++reg) {
      float e = __expf(S_cur[reg]);
      denom[reg] += e;
      int row = (reg & 3) + 8 * (reg >> 2) + 4 * hi;
      sPw[row * 40 + m32] = __float2bfloat16(e);
    }
    asm volatile("s_waitcnt lgkmcnt(0)" ::: "memory");  // wave-local P visibility
    // O += P V (tile it)
    const __hip_bfloat16* sVc = sV[it & 1];
    for (int kc = 0; kc < 2; ++kc) {
      short8 pf = *(const short8*)(sPw + m32 * 40 + kc * 16 + hi * 8);
      for (int vi = 0; vi < 4; ++vi) {
        int rd = vi * 32 + m32;
        int c = kc * 2 + hi;
        short8 vf = *(const short8*)(sVc + rd * 32 + ((c ^ ((rd >> 1) & 3)) << 3));
        oacc[vi] = __builtin_amdgcn_mfma_f32_32x32x16_bf16(pf, vf, oacc[vi], 0, 0, 0);
      }
    }
    __syncthreads();  // drains staging vmcnt + guards sK/sV/sP reuse
    S_cur = S_next;
  }
#undef STAGE_K
#undef STAGE_V

  // partial denom: reduce across the 32 ctx-col lanes
  for (int reg = 0; reg < 16; ++reg)
    for (int off = 1; off < 32; off <<= 1)
      denom[reg] += __shfl_xor(denom[reg], off);

  float* Opb = Op + ((size_t)(half * 16 + bh) * 2048 + nt * 128 + wave * 32) * 128;
  float* denb = den + (size_t)(half * 16 + bh) * 2048 + nt * 128 + wave * 32;
  for (int vi = 0; vi < 4; ++vi)
    for (int reg = 0; reg < 16; ++reg) {
      int row = (reg & 3) + 8 * (reg >> 2) + 4 * hi;
      Opb[(size_t)row * 128 + vi * 32 + m32] = oacc[vi][reg];
    }
  if (m32 == 0)
    for (int reg = 0; reg < 16; ++reg)
      denb[(reg & 3) + 8 * (reg >> 2) + 4 * hi] = denom[reg];
}

// ---------------- combine ctx halves -> bf16 ob ------------------------------
__global__ __launch_bounds__(256) void combine(
    const float* __restrict__ Op, const float* __restrict__ den,
    __hip_bfloat16* __restrict__ ob)
{
  int qi = blockIdx.x * 256 + threadIdx.x;   // 1,048,576 float4-quads
  int r = qi >> 5, dq = qi & 31;
  int bh = r >> 11, n = r & 2047, b = bh >> 2, h = bh & 3;
  float4 o0 = ((const float4*)Op)[qi];
  float4 o1 = ((const float4*)(Op + 4194304))[qi];
  float inv = 1.0f / (den[r] + den[32768 + r]);
  union { __hip_bfloat16 h4[4]; uint2 u; } o;
  o.h4[0] = __float2bfloat16((o0.x + o1.x) * inv);
  o.h4[1] = __float2bfloat16((o0.y + o1.y) * inv);
  o.h4[2] = __float2bfloat16((o0.z + o1.z) * inv);
  o.h4[3] = __float2bfloat16((o0.w + o1.w) * inv);
  *(uint2*)&ob[((size_t)b * 2048 + n) * 512 + h * 128 + dq * 4] = o.u;
}

// ---------------- launch ------------------------------------------------------
extern "C" void kernel_launch(void* const* d_in, const int* in_sizes, int n_in,
                              void* d_out, int out_size, void* d_ws, size_t ws_size,
                              hipStream_t stream) {
  const float* x      = (const float*)d_in[0];
  const float* ctx    = (const float*)d_in[1];
  const float* wqkv   = (const float*)d_in[2];
  const float* wproj  = (const float*)d_in[3];
  const float* radius = (const float*)d_in[4];
  char* ws = (char*)d_ws;
  __hip_bfloat16* ab  = (__hip_bfloat16*)(ws);              // 16 MB (x+ctx bf16)
  __hip_bfloat16* wb  = (__hip_bfloat16*)(ws + 16777216);   // 1 MB
  __hip_bfloat16* wpb = (__hip_bfloat16*)(ws + 17825792);   // 0.5 MB
  __hip_bfloat16* proj= (__hip_bfloat16*)(ws + 18350080);   // 33.5 MB bf16 (dead after normalize)
  float*          Op  = (float*)(ws + 18350080);            // 33.5 MB partial O (reuse)
  float*          den = (float*)(ws + 51904512);            // 256 KB partial denom
  __hip_bfloat16* qn  = (__hip_bfloat16*)(ws + 85458944);   // 16 MB
  __hip_bfloat16* kn  = (__hip_bfloat16*)(ws + 102236160);  // 16 MB
  __hip_bfloat16* vt  = (__hip_bfloat16*)(ws + 119013376);  // 8 MB
  __hip_bfloat16* ob  = (__hip_bfloat16*)(ws + 127401984);  // 8 MB
  float* out = (float*)d_out;

  convert_xw<<<4864, 256, 0, stream>>>(x, wqkv, wproj, ab, wb, wpb);
  ctx_pack<<<1024, 256, 0, stream>>>(ctx, vt, ab);
  gemm_nt<__hip_bfloat16><<<1024, 256, 0, stream>>>(ab, wb, proj, 1024, 512, 8);
  normalize_qk<<<16384, 256, 0, stream>>>(proj, radius, qn, kn);
  attn<<<512, 256, 0, stream>>>(qn, kn, vt, Op, den);
  combine<<<4096, 256, 0, stream>>>(Op, den, ob);
  gemm_nt<float><<<256, 256, 0, stream>>>(ob, wpb, out, 512, 512, 4);
}